// Round 6
// baseline (248.403 us; speedup 1.0000x reference)
//
#include <hip/hip_runtime.h>
#include <limits.h>
#include <math.h>
#include <stdint.h>

// Problem constants (fixed by setup_inputs): x[128][262144] fp32, topk=5.
#define BROWS 128
#define NCOLS (256 * 32 * 32)        // 262144 elements per row
#define K 5
#define BPR 32                       // chunks per row -> 4096 chunks total
#define TPB 256
#define CHUNK (NCOLS / BPR)          // 8192 elements per chunk
#define C4 (CHUNK / 4)               // 2048 float4 per chunk
#define F4T (C4 / TPB)               // 8 float4 per thread per chunk
#define WPR (BPR * 4)                // wave-chunks per row = 128
#define SBLK 512                     // persistent stream blocks (2 per CU)
#define ITERS ((BROWS * BPR) / SBLK) // 8 chunks per block
#define NFLAG 16                     // flagged-chunk capacity (expect ~5)
#define CAP 256                      // candidate capacity (expect ~10)

typedef float v4f __attribute__((ext_vector_type(4)));

// ---- packed 64-bit candidate key: [sortable_f32 : 32][~index : 32] ----
// bigger key == better (value desc, then index asc) -> matches jax.lax.top_k.
__device__ __forceinline__ uint64_t make_key(float f, uint32_t idx) {
    uint32_t u = __float_as_uint(f);
    u = (u & 0x80000000u) ? ~u : (u | 0x80000000u);   // monotone fp32 -> u32
    return ((uint64_t)u << 32) | (uint32_t)(~idx);
}
__device__ __forceinline__ uint32_t key_idx(uint64_t k) { return ~(uint32_t)k; }

#define KEY_NEG_INF 0x007FFFFF00000000ULL  // make_key(-INFINITY, 0xFFFFFFFF)

__device__ __forceinline__ void insert5(uint64_t (&key)[K], uint64_t c) {
    if (c > key[K - 1]) {
        key[K - 1] = c;
#pragma unroll
        for (int s = K - 1; s > 0; --s) {
            if (key[s] > key[s - 1]) {
                uint64_t t = key[s]; key[s] = key[s - 1]; key[s - 1] = t;
            }
        }
    }
}

__device__ __forceinline__ void wave_reduce5(uint64_t (&key)[K]) {
#pragma unroll
    for (int off = 1; off < 64; off <<= 1) {
        uint64_t ok[K];
#pragma unroll
        for (int k = 0; k < K; ++k)
            ok[k] = __shfl_xor((unsigned long long)key[k], off, 64);
#pragma unroll
        for (int k = 0; k < K; ++k) insert5(key, ok[k]);
    }
}

// float top-5 insert (values only, for the threshold)
__device__ __forceinline__ void insert5f(float (&v)[K], float c) {
    if (c > v[K - 1]) {
        v[K - 1] = c;
#pragma unroll
        for (int s = K - 1; s > 0; --s) {
            if (v[s] > v[s - 1]) { float t = v[s]; v[s] = v[s - 1]; v[s - 1] = t; }
        }
    }
}

// K1: persistent, software-pipelined stream. Each block owns 8 consecutive
// chunks; per iteration: issue next-chunk loads (load-ahead), issue the
// independent nt zero-stores for the current chunk, then reduce the current
// chunk's registers (counted vmcnt, never a full drain) and emit per-wave
// maxes. Store-drain + wave-turnover cost amortizes over 128 KB instead of
// 16 KB -> sustained issue like the 6.6 TB/s fill kernel.
__global__ __launch_bounds__(TPB) void wta_stream(const float* __restrict__ x,
                                                  float* __restrict__ out,
                                                  float* __restrict__ wmax) {
    const int b = blockIdx.x;
    const int t = threadIdx.x;
    const int lane = t & 63, w = t >> 6;
    const int c0 = b * ITERS;                 // first chunk of this block
    const float4* __restrict__ x4 = (const float4*)x;
    v4f* __restrict__ o4 = (v4f*)out;
    const v4f z = {0.f, 0.f, 0.f, 0.f};
    const size_t base0 = (size_t)c0 * C4;

    float4 a[F4T];
#pragma unroll
    for (int j = 0; j < F4T; ++j) a[j] = x4[base0 + t + j * TPB];

#pragma unroll 1
    for (int it = 0; it < ITERS - 1; ++it) {
        const size_t cb = base0 + (size_t)it * C4;
        // load-ahead: next chunk
        float4 nb[F4T];
#pragma unroll
        for (int j = 0; j < F4T; ++j) nb[j] = x4[cb + C4 + t + j * TPB];
        // independent zero-stores for current chunk
#pragma unroll
        for (int j = 0; j < F4T; ++j)
            __builtin_nontemporal_store(z, &o4[cb + t + j * TPB]);
        // reduce current chunk (loads are iteration-old: counted wait only)
        float M = -INFINITY;
#pragma unroll
        for (int j = 0; j < F4T; ++j)
            M = fmaxf(M, fmaxf(fmaxf(a[j].x, a[j].y), fmaxf(a[j].z, a[j].w)));
#pragma unroll
        for (int off = 1; off < 64; off <<= 1)
            M = fmaxf(M, __shfl_xor(M, off, 64));
        if (lane == 0) wmax[(c0 + it) * 4 + w] = M;
#pragma unroll
        for (int j = 0; j < F4T; ++j) a[j] = nb[j];
    }

    // final chunk: stores + reduce, no load-ahead
    {
        const size_t cb = base0 + (size_t)(ITERS - 1) * C4;
#pragma unroll
        for (int j = 0; j < F4T; ++j)
            __builtin_nontemporal_store(z, &o4[cb + t + j * TPB]);
        float M = -INFINITY;
#pragma unroll
        for (int j = 0; j < F4T; ++j)
            M = fmaxf(M, fmaxf(fmaxf(a[j].x, a[j].y), fmaxf(a[j].z, a[j].w)));
#pragma unroll
        for (int off = 1; off < 64; off <<= 1)
            M = fmaxf(M, __shfl_xor(M, off, 64));
        if (lane == 0) wmax[(c0 + ITERS - 1) * 4 + w] = M;
    }
}

// K2: one block per row. T = 5th-largest of the row's 128 wave-maxes. Since T
// is the min of 5 actual elements, V5(row) >= T, and every true top-5 element
// sits in a chunk with wmax >= T. Rescan only those (~5) chunks (LLC-resident),
// collect all elements >= T as u64 keys, exact top-5, scatter five 1.0 stores.
__global__ __launch_bounds__(TPB) void wta_finish(const float* __restrict__ x,
                                                  const float* __restrict__ wmax,
                                                  float* __restrict__ out) {
    const int row = blockIdx.x;
    const int t = threadIdx.x;
    const float* __restrict__ wm = wmax + row * WPR;

    __shared__ float sT;
    __shared__ int nflag, ncand;
    __shared__ int flaglist[NFLAG];
    __shared__ uint64_t cand[CAP];

    if (t == 0) { nflag = 0; ncand = 0; }
    __syncthreads();

    // ---- threshold: top-5 of 128 wave-maxes (first wave only) ----
    if (t < 64) {
        float v[K];
#pragma unroll
        for (int k = 0; k < K; ++k) v[k] = -INFINITY;
        insert5f(v, wm[t]);
        insert5f(v, wm[t + 64]);
#pragma unroll
        for (int off = 1; off < 64; off <<= 1) {
            float ov[K];
#pragma unroll
            for (int k = 0; k < K; ++k) ov[k] = __shfl_xor(v[k], off, 64);
#pragma unroll
            for (int k = 0; k < K; ++k) insert5f(v, ov[k]);
        }
        if (t == 0) sT = v[K - 1];
    }
    __syncthreads();
    const float T = sT;

    // ---- flag chunks with wmax >= T (expect ~5) ----
    if (t < WPR && wm[t] >= T) {
        const int s = atomicAdd(&nflag, 1);
        if (s < NFLAG) flaglist[s] = t;
    }
    __syncthreads();
    const int nf = min(nflag, NFLAG);

    // ---- rescan flagged chunks (coalesced, LLC-hot), collect survivors ----
    const int lane = t & 63, jj = t >> 6;
    for (int f = 0; f < nf; ++f) {
        const int wid = flaglist[f];
        const int gbk = wid >> 2;          // chunk within row
        const int w   = wid & 3;           // wave within chunk
        const float4* __restrict__ xb =
            (const float4*)(x + (size_t)row * NCOLS + (size_t)gbk * CHUNK);
#pragma unroll
        for (int rep = 0; rep < 2; ++rep) {
            const int j = jj + rep * 4;
            const int f4pos = w * 64 + lane + j * TPB;
            const float4 d = xb[f4pos];
            const float vs[4] = {d.x, d.y, d.z, d.w};
#pragma unroll
            for (int c = 0; c < 4; ++c) {
                if (vs[c] >= T) {
                    const int s = atomicAdd(&ncand, 1);
                    if (s < CAP)
                        cand[s] = make_key(vs[c],
                                           (uint32_t)gbk * CHUNK + (uint32_t)f4pos * 4u + c);
                }
            }
        }
    }
    __syncthreads();

    // ---- exact top-5 of survivors, scatter ones ----
    if (t < 64) {
        const int n = min(ncand, CAP);
        uint64_t key[K];
#pragma unroll
        for (int k = 0; k < K; ++k) key[k] = KEY_NEG_INF;
        for (int i = t; i < n; i += 64) insert5(key, cand[i]);
        wave_reduce5(key);
        if (t == 0) {
#pragma unroll
            for (int k = 0; k < K; ++k)
                if (key[k] != KEY_NEG_INF)
                    out[(size_t)row * NCOLS + key_idx(key[k])] = 1.0f;
        }
    }
}

extern "C" void kernel_launch(void* const* d_in, const int* in_sizes, int n_in,
                              void* d_out, int out_size, void* d_ws, size_t ws_size,
                              hipStream_t stream) {
    const float* x = (const float*)d_in[0];
    float* out = (float*)d_out;

    // ws layout: wmax (4096 chunks * 4 waves f32 = 64 KiB)
    float* wmax = (float*)d_ws;

    wta_stream<<<SBLK, TPB, 0, stream>>>(x, out, wmax);
    wta_finish<<<BROWS, TPB, 0, stream>>>(x, wmax, out);
}

// Round 7
// 245.077 us; speedup vs baseline: 1.0136x; 1.0136x over previous
//
#include <hip/hip_runtime.h>
#include <limits.h>
#include <math.h>
#include <stdint.h>

// Problem constants (fixed by setup_inputs): x[128][262144] fp32, topk=5.
#define BROWS 128
#define NCOLS (256 * 32 * 32)        // 262144 elements per row
#define K 5
#define BPR 32                       // chunks per row -> 4096 chunks total
#define TPB 256
#define CHUNK (NCOLS / BPR)          // 8192 elements per chunk
#define C4 (CHUNK / 4)               // 2048 float4 per chunk
#define F4T (C4 / TPB)               // 8 float4 per thread per chunk
#define WPR (BPR * 4)                // wave-chunks per row = 128
#define FBLK 2048                    // fill grid (matches rocclr fill shape)
#define NFLAG 16                     // flagged-chunk capacity (expect ~5)
#define CAP 256                      // candidate capacity (expect ~10)

typedef float v4f __attribute__((ext_vector_type(4)));

// ---- packed 64-bit candidate key: [sortable_f32 : 32][~index : 32] ----
// bigger key == better (value desc, then index asc) -> matches jax.lax.top_k.
__device__ __forceinline__ uint64_t make_key(float f, uint32_t idx) {
    uint32_t u = __float_as_uint(f);
    u = (u & 0x80000000u) ? ~u : (u | 0x80000000u);   // monotone fp32 -> u32
    return ((uint64_t)u << 32) | (uint32_t)(~idx);
}
__device__ __forceinline__ uint32_t key_idx(uint64_t k) { return ~(uint32_t)k; }

#define KEY_NEG_INF 0x007FFFFF00000000ULL  // make_key(-INFINITY, 0xFFFFFFFF)

__device__ __forceinline__ void insert5(uint64_t (&key)[K], uint64_t c) {
    if (c > key[K - 1]) {
        key[K - 1] = c;
#pragma unroll
        for (int s = K - 1; s > 0; --s) {
            if (key[s] > key[s - 1]) {
                uint64_t t = key[s]; key[s] = key[s - 1]; key[s - 1] = t;
            }
        }
    }
}

__device__ __forceinline__ void wave_reduce5(uint64_t (&key)[K]) {
#pragma unroll
    for (int off = 1; off < 64; off <<= 1) {
        uint64_t ok[K];
#pragma unroll
        for (int k = 0; k < K; ++k)
            ok[k] = __shfl_xor((unsigned long long)key[k], off, 64);
#pragma unroll
        for (int k = 0; k < K; ++k) insert5(key, ok[k]);
    }
}

// float top-5 insert (values only, for the threshold)
__device__ __forceinline__ void insert5f(float (&v)[K], float c) {
    if (c > v[K - 1]) {
        v[K - 1] = c;
#pragma unroll
        for (int s = K - 1; s > 0; --s) {
            if (v[s] > v[s - 1]) { float t = v[s]; v[s] = v[s - 1]; v[s - 1] = t; }
        }
    }
}

// K0: pure-write zero-fill of out. Grid-stride, plain float4 stores — the
// exact structure the rocclr fill kernel uses to hit 6.6 TB/s on this chip.
// No loads in the vmcnt stream, no waits, stores never drained by a consumer.
__global__ __launch_bounds__(TPB) void wta_fill(float* __restrict__ out) {
    const size_t total = (size_t)BROWS * NCOLS / 4;   // 8.4M float4
    v4f* __restrict__ o4 = (v4f*)out;
    const v4f z = {0.f, 0.f, 0.f, 0.f};
    for (size_t p = (size_t)blockIdx.x * TPB + threadIdx.x; p < total;
         p += (size_t)FBLK * TPB)
        o4[p] = z;
}

// K1: pure-read max-scan. Per wave: 8 float4 loads -> one counted wait ->
// 31 fmax + 6 shfl-fmax -> one scalar wmax store. No store stream mixed into
// the wait path, 63% occupancy, huge MLP margin.
__global__ __launch_bounds__(TPB) void wta_scan(const float* __restrict__ x,
                                                float* __restrict__ wmax) {
    const int gb = blockIdx.x;
    const size_t base = (size_t)gb * C4;
    const float4* __restrict__ x4 = (const float4*)x + base;
    const int t = threadIdx.x;
    const int lane = t & 63, w = t >> 6;

    float4 d[F4T];
#pragma unroll
    for (int j = 0; j < F4T; ++j) d[j] = x4[t + j * TPB];

    float M = -INFINITY;
#pragma unroll
    for (int j = 0; j < F4T; ++j)
        M = fmaxf(M, fmaxf(fmaxf(d[j].x, d[j].y), fmaxf(d[j].z, d[j].w)));
#pragma unroll
    for (int off = 1; off < 64; off <<= 1)
        M = fmaxf(M, __shfl_xor(M, off, 64));

    if (lane == 0) wmax[gb * 4 + w] = M;   // wave-chunk max
}

// K2: one block per row. T = 5th-largest of the row's 128 wave-maxes. Since T
// is the min of 5 actual elements, V5(row) >= T, and every true top-5 element
// sits in a chunk with wmax >= T. Rescan only those (~5) chunks (LLC-resident),
// collect all elements >= T as u64 keys, exact top-5, scatter five 1.0 stores.
__global__ __launch_bounds__(TPB) void wta_finish(const float* __restrict__ x,
                                                  const float* __restrict__ wmax,
                                                  float* __restrict__ out) {
    const int row = blockIdx.x;
    const int t = threadIdx.x;
    const float* __restrict__ wm = wmax + row * WPR;

    __shared__ float sT;
    __shared__ int nflag, ncand;
    __shared__ int flaglist[NFLAG];
    __shared__ uint64_t cand[CAP];

    if (t == 0) { nflag = 0; ncand = 0; }
    __syncthreads();

    // ---- threshold: top-5 of 128 wave-maxes (first wave only) ----
    if (t < 64) {
        float v[K];
#pragma unroll
        for (int k = 0; k < K; ++k) v[k] = -INFINITY;
        insert5f(v, wm[t]);
        insert5f(v, wm[t + 64]);
#pragma unroll
        for (int off = 1; off < 64; off <<= 1) {
            float ov[K];
#pragma unroll
            for (int k = 0; k < K; ++k) ov[k] = __shfl_xor(v[k], off, 64);
#pragma unroll
            for (int k = 0; k < K; ++k) insert5f(v, ov[k]);
        }
        if (t == 0) sT = v[K - 1];
    }
    __syncthreads();
    const float T = sT;

    // ---- flag chunks with wmax >= T (expect ~5) ----
    if (t < WPR && wm[t] >= T) {
        const int s = atomicAdd(&nflag, 1);
        if (s < NFLAG) flaglist[s] = t;
    }
    __syncthreads();
    const int nf = min(nflag, NFLAG);

    // ---- rescan flagged chunks (coalesced, LLC-hot), collect survivors ----
    const int lane = t & 63, jj = t >> 6;
    for (int f = 0; f < nf; ++f) {
        const int wid = flaglist[f];
        const int gbk = wid >> 2;          // chunk within row
        const int w   = wid & 3;           // wave within chunk
        const float4* __restrict__ xb =
            (const float4*)(x + (size_t)row * NCOLS + (size_t)gbk * CHUNK);
#pragma unroll
        for (int rep = 0; rep < 2; ++rep) {
            const int j = jj + rep * 4;
            const int f4pos = w * 64 + lane + j * TPB;
            const float4 d = xb[f4pos];
            const float vs[4] = {d.x, d.y, d.z, d.w};
#pragma unroll
            for (int c = 0; c < 4; ++c) {
                if (vs[c] >= T) {
                    const int s = atomicAdd(&ncand, 1);
                    if (s < CAP)
                        cand[s] = make_key(vs[c],
                                           (uint32_t)gbk * CHUNK + (uint32_t)f4pos * 4u + c);
                }
            }
        }
    }
    __syncthreads();

    // ---- exact top-5 of survivors, scatter ones ----
    if (t < 64) {
        const int n = min(ncand, CAP);
        uint64_t key[K];
#pragma unroll
        for (int k = 0; k < K; ++k) key[k] = KEY_NEG_INF;
        for (int i = t; i < n; i += 64) insert5(key, cand[i]);
        wave_reduce5(key);
        if (t == 0) {
#pragma unroll
            for (int k = 0; k < K; ++k)
                if (key[k] != KEY_NEG_INF)
                    out[(size_t)row * NCOLS + key_idx(key[k])] = 1.0f;
        }
    }
}

extern "C" void kernel_launch(void* const* d_in, const int* in_sizes, int n_in,
                              void* d_out, int out_size, void* d_ws, size_t ws_size,
                              hipStream_t stream) {
    const float* x = (const float*)d_in[0];
    float* out = (float*)d_out;

    // ws layout: wmax (4096 chunks * 4 waves f32 = 64 KiB)
    float* wmax = (float*)d_ws;

    wta_fill<<<FBLK, TPB, 0, stream>>>(out);
    wta_scan<<<BROWS * BPR, TPB, 0, stream>>>(x, wmax);
    wta_finish<<<BROWS, TPB, 0, stream>>>(x, wmax, out);
}

// Round 9
// 243.603 us; speedup vs baseline: 1.0197x; 1.0061x over previous
//
#include <hip/hip_runtime.h>
#include <limits.h>
#include <math.h>
#include <stdint.h>

// Problem constants (fixed by setup_inputs): x[128][262144] fp32, topk=5.
#define BROWS 128
#define NCOLS (256 * 32 * 32)        // 262144 elements per row
#define K 5
#define BPR 32                       // chunks per row -> 4096 chunks total
#define TPB 256
#define CHUNK (NCOLS / BPR)          // 8192 elements per chunk
#define C4 (CHUNK / 4)               // 2048 float4 per chunk
#define F4T (C4 / TPB)               // 8 float4 per thread per chunk
#define WPR (BPR * 4)                // wave-chunks per row = 128
#define NFLAG 16                     // flagged-chunk capacity (expect ~5)
#define CAP 256                      // candidate capacity (expect ~10)

typedef float v4f __attribute__((ext_vector_type(4)));

// ---- packed 64-bit candidate key: [sortable_f32 : 32][~index : 32] ----
// bigger key == better (value desc, then index asc) -> matches jax.lax.top_k.
__device__ __forceinline__ uint64_t make_key(float f, uint32_t idx) {
    uint32_t u = __float_as_uint(f);
    u = (u & 0x80000000u) ? ~u : (u | 0x80000000u);   // monotone fp32 -> u32
    return ((uint64_t)u << 32) | (uint32_t)(~idx);
}
__device__ __forceinline__ uint32_t key_idx(uint64_t k) { return ~(uint32_t)k; }

#define KEY_NEG_INF 0x007FFFFF00000000ULL  // make_key(-INFINITY, 0xFFFFFFFF)

__device__ __forceinline__ void insert5(uint64_t (&key)[K], uint64_t c) {
    if (c > key[K - 1]) {
        key[K - 1] = c;
#pragma unroll
        for (int s = K - 1; s > 0; --s) {
            if (key[s] > key[s - 1]) {
                uint64_t t = key[s]; key[s] = key[s - 1]; key[s - 1] = t;
            }
        }
    }
}

__device__ __forceinline__ void wave_reduce5(uint64_t (&key)[K]) {
#pragma unroll
    for (int off = 1; off < 64; off <<= 1) {
        uint64_t ok[K];
#pragma unroll
        for (int k = 0; k < K; ++k)
            ok[k] = __shfl_xor((unsigned long long)key[k], off, 64);
#pragma unroll
        for (int k = 0; k < K; ++k) insert5(key, ok[k]);
    }
}

// float top-5 insert (values only, for the threshold)
__device__ __forceinline__ void insert5f(float (&v)[K], float c) {
    if (c > v[K - 1]) {
        v[K - 1] = c;
#pragma unroll
        for (int s = K - 1; s > 0; --s) {
            if (v[s] > v[s - 1]) { float t = v[s]; v[s] = v[s - 1]; v[s - 1] = t; }
        }
    }
}

// K1: fused streaming pass — IDENTICAL to the R3 structure that measured
// 81.7 us, except the zero-stores are PLAIN float4 stores (L2 write path)
// instead of __builtin_nontemporal_store. Single-variable A/B: every fast
// writer on this chip (rocclr fill 6.77 TB/s, m13 copy 6.29 TB/s) uses plain
// stores; every ~3.3 TB/s variant of ours used nt.
__global__ __launch_bounds__(TPB) void wta_stream(const float* __restrict__ x,
                                                  float* __restrict__ out,
                                                  float* __restrict__ wmax) {
    const int gb = blockIdx.x;
    const size_t base = (size_t)gb * C4;
    const float4* __restrict__ x4 = (const float4*)x + base;
    float4* __restrict__ o4 = (float4*)out + base;
    const int t = threadIdx.x;
    const int lane = t & 63, w = t >> 6;
    const float4 z = {0.f, 0.f, 0.f, 0.f};

    float4 d[F4T];
#pragma unroll
    for (int j = 0; j < F4T; ++j) d[j] = x4[t + j * TPB];
#pragma unroll
    for (int j = 0; j < F4T; ++j) o4[t + j * TPB] = z;   // plain stores

    float M = -INFINITY;
#pragma unroll
    for (int j = 0; j < F4T; ++j)
        M = fmaxf(M, fmaxf(fmaxf(d[j].x, d[j].y), fmaxf(d[j].z, d[j].w)));
#pragma unroll
    for (int off = 1; off < 64; off <<= 1)
        M = fmaxf(M, __shfl_xor(M, off, 64));

    if (lane == 0) wmax[gb * 4 + w] = M;   // wave-chunk max
}

// K2: one block per row. T = 5th-largest of the row's 128 wave-maxes. Since T
// is the min of 5 actual elements, V5(row) >= T, and every true top-5 element
// sits in a chunk with wmax >= T. Rescan only those (~5) chunks (cache-hot),
// collect all elements >= T as u64 keys, exact top-5, scatter five 1.0 stores.
__global__ __launch_bounds__(TPB) void wta_finish(const float* __restrict__ x,
                                                  const float* __restrict__ wmax,
                                                  float* __restrict__ out) {
    const int row = blockIdx.x;
    const int t = threadIdx.x;
    const float* __restrict__ wm = wmax + row * WPR;

    __shared__ float sT;
    __shared__ int nflag, ncand;
    __shared__ int flaglist[NFLAG];
    __shared__ uint64_t cand[CAP];

    if (t == 0) { nflag = 0; ncand = 0; }
    __syncthreads();

    // ---- threshold: top-5 of 128 wave-maxes (first wave only) ----
    if (t < 64) {
        float v[K];
#pragma unroll
        for (int k = 0; k < K; ++k) v[k] = -INFINITY;
        insert5f(v, wm[t]);
        insert5f(v, wm[t + 64]);
#pragma unroll
        for (int off = 1; off < 64; off <<= 1) {
            float ov[K];
#pragma unroll
            for (int k = 0; k < K; ++k) ov[k] = __shfl_xor(v[k], off, 64);
#pragma unroll
            for (int k = 0; k < K; ++k) insert5f(v, ov[k]);
        }
        if (t == 0) sT = v[K - 1];
    }
    __syncthreads();
    const float T = sT;

    // ---- flag chunks with wmax >= T (expect ~5) ----
    if (t < WPR && wm[t] >= T) {
        const int s = atomicAdd(&nflag, 1);
        if (s < NFLAG) flaglist[s] = t;
    }
    __syncthreads();
    const int nf = min(nflag, NFLAG);

    // ---- rescan flagged chunks (coalesced, cache-hot), collect survivors ----
    const int lane = t & 63, jj = t >> 6;
    for (int f = 0; f < nf; ++f) {
        const int wid = flaglist[f];
        const int gbk = wid >> 2;          // chunk within row
        const int w   = wid & 3;           // wave within chunk
        const float4* __restrict__ xb =
            (const float4*)(x + (size_t)row * NCOLS + (size_t)gbk * CHUNK);
#pragma unroll
        for (int rep = 0; rep < 2; ++rep) {
            const int j = jj + rep * 4;
            const int f4pos = w * 64 + lane + j * TPB;
            const float4 d = xb[f4pos];
            const float vs[4] = {d.x, d.y, d.z, d.w};
#pragma unroll
            for (int c = 0; c < 4; ++c) {
                if (vs[c] >= T) {
                    const int s = atomicAdd(&ncand, 1);
                    if (s < CAP)
                        cand[s] = make_key(vs[c],
                                           (uint32_t)gbk * CHUNK + (uint32_t)f4pos * 4u + c);
                }
            }
        }
    }
    __syncthreads();

    // ---- exact top-5 of survivors, scatter ones ----
    if (t < 64) {
        const int n = min(ncand, CAP);
        uint64_t key[K];
#pragma unroll
        for (int k = 0; k < K; ++k) key[k] = KEY_NEG_INF;
        for (int i = t; i < n; i += 64) insert5(key, cand[i]);
        wave_reduce5(key);
        if (t == 0) {
#pragma unroll
            for (int k = 0; k < K; ++k)
                if (key[k] != KEY_NEG_INF)
                    out[(size_t)row * NCOLS + key_idx(key[k])] = 1.0f;
        }
    }
}

extern "C" void kernel_launch(void* const* d_in, const int* in_sizes, int n_in,
                              void* d_out, int out_size, void* d_ws, size_t ws_size,
                              hipStream_t stream) {
    const float* x = (const float*)d_in[0];
    float* out = (float*)d_out;

    // ws layout: wmax (4096 chunks * 4 waves f32 = 64 KiB)
    float* wmax = (float*)d_ws;

    wta_stream<<<BROWS * BPR, TPB, 0, stream>>>(x, out, wmax);
    wta_finish<<<BROWS, TPB, 0, stream>>>(x, wmax, out);
}